// Round 5
// baseline (45.199 us; speedup 1.0000x reference)
//
#include <hip/hip_runtime.h>

// FrequencyAdaptiveNorm: per-timestep LayerNorm(F=256) + mask-weighted affine.
// x: (B=32, S=4096, F=256) f32; gamma,beta: (3,256) f32; weights: (3,) f32.
//
// Round-5: RPW=8 rows per wave, all 8 x-loads issued before the first
// reduction (128 B/lane in flight). gamma/beta + softmax + interior combo
// hoisted once per wave. Nontemporal stores. 4096 blocks.

#define S_LEN 4096
#define F_LEN 256
#define EPSV 1e-5f
#define RPW 8                       // rows per wave

typedef float f32x4 __attribute__((ext_vector_type(4)));

__global__ __launch_bounds__(256) void fan_ln_kernel(
    const float* __restrict__ x,
    const float* __restrict__ gamma,
    const float* __restrict__ beta,
    const float* __restrict__ weights,
    float* __restrict__ out,
    int n_rows)
{
    const int wave = threadIdx.x >> 6;
    const int lane = threadIdx.x & 63;
    const int row0 = (blockIdx.x * 4 + wave) * RPW;
    if (row0 >= n_rows) return;

    // ---- prefetch all 8 row fragments (128 B/lane in flight) ----
    f32x4 xv[RPW];
    #pragma unroll
    for (int r = 0; r < RPW; ++r)
        xv[r] = reinterpret_cast<const f32x4*>(x + (size_t)(row0 + r) * F_LEN)[lane];

    // ---- once per wave: softmax of the 3 logits ----
    const float l0 = weights[0], l1 = weights[1], l2 = weights[2];
    const float mx = fmaxf(l0, fmaxf(l1, l2));
    const float e0 = expf(l0 - mx), e1 = expf(l1 - mx), e2 = expf(l2 - mx);
    const float inv = 1.0f / (e0 + e1 + e2);
    const float w0 = e0 * inv, w1 = e1 * inv, w2 = e2 * inv;

    // ---- once per wave: gamma/beta + interior combination ----
    const f32x4 g0 = reinterpret_cast<const f32x4*>(gamma + 0 * F_LEN)[lane];
    const f32x4 g1 = reinterpret_cast<const f32x4*>(gamma + 1 * F_LEN)[lane];
    const f32x4 g2 = reinterpret_cast<const f32x4*>(gamma + 2 * F_LEN)[lane];
    const f32x4 b0 = reinterpret_cast<const f32x4*>(beta  + 0 * F_LEN)[lane];
    const f32x4 b1 = reinterpret_cast<const f32x4*>(beta  + 1 * F_LEN)[lane];
    const f32x4 b2 = reinterpret_cast<const f32x4*>(beta  + 2 * F_LEN)[lane];
    const f32x4 G3 = w0 * g0 + w1 * g1 + w2 * g2;   // all-windows-valid combo
    const f32x4 B3 = w0 * b0 + w1 * b1 + w2 * b2;

    #pragma unroll
    for (int r = 0; r < RPW; ++r) {
        const f32x4 v = xv[r];
        const int row = row0 + r;
        const int t = row & (S_LEN - 1);

        float s  = (v.x + v.y) + (v.z + v.w);
        float sq = (v.x*v.x + v.y*v.y) + (v.z*v.z + v.w*v.w);
        #pragma unroll
        for (int off = 32; off >= 1; off >>= 1) {
            s  += __shfl_xor(s,  off);
            sq += __shfl_xor(sq, off);
        }
        const float mean = s * (1.0f / F_LEN);
        const float var  = sq * (1.0f / F_LEN) - mean * mean;
        const float rstd = rsqrtf(var + EPSV);

        f32x4 G, Bv;
        if (t >= 10 && t < 4087) {          // interior: wave-uniform fast path
            G = G3; Bv = B3;
        } else {                            // border: 19 of 4096 timesteps
            const float m0 = (t >= 2  && t < 4094) ? w0 : 0.0f;
            const float m1 = (t >= 5  && t < 4092) ? w1 : 0.0f;
            const float m2 = (t >= 10 && t < 4087) ? w2 : 0.0f;
            G  = m0 * g0 + m1 * g1 + m2 * g2;
            Bv = m0 * b0 + m1 * b1 + m2 * b2;
        }

        f32x4 ov;
        ov.x = (v.x - mean) * rstd * G.x + Bv.x;
        ov.y = (v.y - mean) * rstd * G.y + Bv.y;
        ov.z = (v.z - mean) * rstd * G.z + Bv.z;
        ov.w = (v.w - mean) * rstd * G.w + Bv.w;

        __builtin_nontemporal_store(
            ov, reinterpret_cast<f32x4*>(out + (size_t)row * F_LEN) + lane);
    }
}

extern "C" void kernel_launch(void* const* d_in, const int* in_sizes, int n_in,
                              void* d_out, int out_size, void* d_ws, size_t ws_size,
                              hipStream_t stream) {
    const float* x       = (const float*)d_in[0];
    const float* gamma   = (const float*)d_in[1];
    const float* beta    = (const float*)d_in[2];
    const float* weights = (const float*)d_in[3];
    float* out = (float*)d_out;

    const int n_rows = out_size / F_LEN;              // B*S = 131072
    const int rows_per_block = 4 * RPW;               // 4 waves x 8 rows
    const int blocks = (n_rows + rows_per_block - 1) / rows_per_block;

    fan_ln_kernel<<<blocks, 256, 0, stream>>>(x, gamma, beta, weights, out, n_rows);
}

// Round 6
// 43.978 us; speedup vs baseline: 1.0278x; 1.0278x over previous
//
#include <hip/hip_runtime.h>

// FrequencyAdaptiveNorm: per-timestep LayerNorm(F=256) + mask-weighted affine.
// x: (B=32, S=4096, F=256) f32; gamma,beta: (3,256) f32; weights: (3,) f32.
//
// FINAL (= round-4 kernel, best measured at 44.1 us ~ 97% of the 6.29 TB/s
// mixed-stream ceiling): 4 rows per wave, all 4 x-loads issued up front;
// softmax + gamma/beta + interior affine combo hoisted once per wave;
// nontemporal stores. RPW=8 measured slower (45.2); RPW=1 measured 46.6.

#define S_LEN 4096
#define F_LEN 256
#define EPSV 1e-5f
#define RPW 4                       // rows per wave (measured optimum)

typedef float f32x4 __attribute__((ext_vector_type(4)));

__global__ __launch_bounds__(256) void fan_ln_kernel(
    const float* __restrict__ x,
    const float* __restrict__ gamma,
    const float* __restrict__ beta,
    const float* __restrict__ weights,
    float* __restrict__ out,
    int n_rows)
{
    const int wave = threadIdx.x >> 6;
    const int lane = threadIdx.x & 63;
    const int row0 = (blockIdx.x * 4 + wave) * RPW;
    if (row0 >= n_rows) return;

    // ---- prefetch all 4 row fragments (64 B/lane in flight) ----
    f32x4 xv0 = reinterpret_cast<const f32x4*>(x + (size_t)(row0 + 0) * F_LEN)[lane];
    f32x4 xv1 = reinterpret_cast<const f32x4*>(x + (size_t)(row0 + 1) * F_LEN)[lane];
    f32x4 xv2 = reinterpret_cast<const f32x4*>(x + (size_t)(row0 + 2) * F_LEN)[lane];
    f32x4 xv3 = reinterpret_cast<const f32x4*>(x + (size_t)(row0 + 3) * F_LEN)[lane];

    // ---- once per wave: softmax of the 3 logits ----
    const float l0 = weights[0], l1 = weights[1], l2 = weights[2];
    const float mx = fmaxf(l0, fmaxf(l1, l2));
    const float e0 = expf(l0 - mx), e1 = expf(l1 - mx), e2 = expf(l2 - mx);
    const float inv = 1.0f / (e0 + e1 + e2);
    const float w0 = e0 * inv, w1 = e1 * inv, w2 = e2 * inv;

    // ---- once per wave: gamma/beta + interior combination ----
    const f32x4 g0 = reinterpret_cast<const f32x4*>(gamma + 0 * F_LEN)[lane];
    const f32x4 g1 = reinterpret_cast<const f32x4*>(gamma + 1 * F_LEN)[lane];
    const f32x4 g2 = reinterpret_cast<const f32x4*>(gamma + 2 * F_LEN)[lane];
    const f32x4 b0 = reinterpret_cast<const f32x4*>(beta  + 0 * F_LEN)[lane];
    const f32x4 b1 = reinterpret_cast<const f32x4*>(beta  + 1 * F_LEN)[lane];
    const f32x4 b2 = reinterpret_cast<const f32x4*>(beta  + 2 * F_LEN)[lane];
    const f32x4 G3 = w0 * g0 + w1 * g1 + w2 * g2;   // all-windows-valid combo
    const f32x4 B3 = w0 * b0 + w1 * b1 + w2 * b2;

    #pragma unroll
    for (int r = 0; r < RPW; ++r) {
        const f32x4 xv = (r == 0) ? xv0 : (r == 1) ? xv1 : (r == 2) ? xv2 : xv3;
        const int row = row0 + r;
        const int t = row & (S_LEN - 1);

        float s  = (xv.x + xv.y) + (xv.z + xv.w);
        float sq = (xv.x*xv.x + xv.y*xv.y) + (xv.z*xv.z + xv.w*xv.w);
        #pragma unroll
        for (int off = 32; off >= 1; off >>= 1) {
            s  += __shfl_xor(s,  off);
            sq += __shfl_xor(sq, off);
        }
        const float mean = s * (1.0f / F_LEN);
        const float var  = sq * (1.0f / F_LEN) - mean * mean;
        const float rstd = rsqrtf(var + EPSV);

        f32x4 G, Bv;
        if (t >= 10 && t < 4087) {          // interior: wave-uniform fast path
            G = G3; Bv = B3;
        } else {                            // border: 19 of 4096 timesteps
            const float m0 = (t >= 2  && t < 4094) ? w0 : 0.0f;
            const float m1 = (t >= 5  && t < 4092) ? w1 : 0.0f;
            const float m2 = (t >= 10 && t < 4087) ? w2 : 0.0f;
            G  = m0 * g0 + m1 * g1 + m2 * g2;
            Bv = m0 * b0 + m1 * b1 + m2 * b2;
        }

        f32x4 ov;
        ov.x = (xv.x - mean) * rstd * G.x + Bv.x;
        ov.y = (xv.y - mean) * rstd * G.y + Bv.y;
        ov.z = (xv.z - mean) * rstd * G.z + Bv.z;
        ov.w = (xv.w - mean) * rstd * G.w + Bv.w;

        __builtin_nontemporal_store(
            ov, reinterpret_cast<f32x4*>(out + (size_t)row * F_LEN) + lane);
    }
}

extern "C" void kernel_launch(void* const* d_in, const int* in_sizes, int n_in,
                              void* d_out, int out_size, void* d_ws, size_t ws_size,
                              hipStream_t stream) {
    const float* x       = (const float*)d_in[0];
    const float* gamma   = (const float*)d_in[1];
    const float* beta    = (const float*)d_in[2];
    const float* weights = (const float*)d_in[3];
    float* out = (float*)d_out;

    const int n_rows = out_size / F_LEN;              // B*S = 131072
    const int rows_per_block = 4 * RPW;               // 4 waves x 4 rows
    const int blocks = (n_rows + rows_per_block - 1) / rows_per_block;

    fan_ln_kernel<<<blocks, 256, 0, stream>>>(x, gamma, beta, weights, out, n_rows);
}